// Round 6
// baseline (304.883 us; speedup 1.0000x reference)
//
#include <hip/hip_runtime.h>
#include <hip/hip_bf16.h>

// Swin block, B=32 H=W=56 C=128, ws=7 (N=49), nh=4 (hd=32), shift=3, hid=512.
// fp32 in/out. All GEMMs AND attention (QK^T, AV) via mfma_f32_16x16x32_bf16.
// roll(-3) gather == roll(+3) scatter target -> fully fused windows.
// R11: LDS diet 76800 -> 54272 B => 3 blocks/CU (24 waves, was 16).
//   - Q and P live in REGISTERS: MFMA D[f][m] -> B-frag[n][d] is a pure
//     quad-group exchange (same l15 token lane): 2 shfl + cndmask per u32.
//     Wave (h,half) computes its own Q n-half (2 of 4 m-tiles) and shuffles
//     softmax'd P in-register -> the 41KB Q/K/P region shrinks to K-only 20.5K.
//   - vT repacked [4][32][64] with XOR block swizzle (block^=(m>>3)^(d&7)):
//     verified 8-accesses/bank optimal on the AV b128 reads.
//   - x2s (33.8K) and double-buffered 4x128-chunk MLP hidden (2x17.4K) overlay
//     the dead K+vT region. Barriers 10 -> 9 (p3 mid-bar gone, p6 dbuf).
//   - __launch_bounds__(512,6): VGPR cap ~85 for 6 waves/SIMD.

#define NWIN 2048

typedef short short8  __attribute__((ext_vector_type(8)));
typedef short short4v __attribute__((ext_vector_type(4)));
typedef float f32x4   __attribute__((ext_vector_type(4)));

union Frag { int i[4]; unsigned u[4]; short8 s; };

#define QKVW_OFF  0        // 384*128 bf16
#define PROJW_OFF 49152    // 128*128
#define W1_OFF    65536    // 512*128
#define W2_OFF    131072   // 128*512
#define BIAS_BYTE_OFF 393216  // biasT[4][64][64] fp32 (padded, 0 outside 49x49)

__device__ __forceinline__ short f2bs(float v) {
  __hip_bfloat16 h = __float2bfloat16(v);
  union { __hip_bfloat16 h; short s; } u; u.h = h; return u.s;
}
__device__ __forceinline__ float gelu_f(float v) {
  float u = v * (0.7978845608028654f + 0.03567740814f * v * v);
  return v * __builtin_amdgcn_rcpf(1.f + __expf(-2.f * u));
}

// ---------------- pre-pass: weights -> bf16, padded bias^T gather ----------------
__global__ __launch_bounds__(256) void conv_kernel(
    const float* __restrict__ qkvw, const float* __restrict__ projw,
    const float* __restrict__ w1,   const float* __restrict__ w2,
    const float* __restrict__ tab,  const int* __restrict__ ridx,
    __hip_bfloat16* __restrict__ wsb, float* __restrict__ biasT)
{
  int idx = blockIdx.x * 256 + threadIdx.x;
  if (idx < 49152)       wsb[QKVW_OFF + idx]          = __float2bfloat16(qkvw[idx]);
  else if (idx < 65536)  wsb[PROJW_OFF + idx - 49152] = __float2bfloat16(projw[idx - 49152]);
  else if (idx < 131072) wsb[W1_OFF + idx - 65536]    = __float2bfloat16(w1[idx - 65536]);
  else if (idx < 196608) wsb[W2_OFF + idx - 131072]   = __float2bfloat16(w2[idx - 131072]);
  else if (idx < 212992) {
    int i = idx - 196608;
    int h = i >> 12, m = (i >> 6) & 63, n = i & 63;   // biasT[h][m=key][n=query]
    biasT[i] = (m < 49 && n < 49) ? tab[ridx[n*49 + m]*4 + h] : 0.f;
  }
}

// ------- fused: LN1 + window attn + proj + shortcut + LN2 + MLP + residual -------
__global__ __launch_bounds__(512, 6) void fused_kernel(
    const float* __restrict__ x,
    const float* __restrict__ n1g, const float* __restrict__ n1b,
    const __hip_bfloat16* __restrict__ qkvwb, const float* __restrict__ qkvb,
    const float* __restrict__ biasT,
    const __hip_bfloat16* __restrict__ projwb, const float* __restrict__ projb,
    const float* __restrict__ n2g, const float* __restrict__ n2b,
    const __hip_bfloat16* __restrict__ w1b, const float* __restrict__ b1,
    const __hip_bfloat16* __restrict__ w2b, const float* __restrict__ b2,
    float* __restrict__ out)
{
  __shared__ alignas(16) __hip_bfloat16 hbuf[64][136];   // 17408 B: h / o / ln2
  __shared__ alignas(16) char shmem[36864];              // K+vT | x2s | hb dbuf
  __hip_bfloat16* const Kl  = (__hip_bfloat16*)shmem;            // [4][64][40]
  __hip_bfloat16* const vTl = (__hip_bfloat16*)(shmem + 20480);  // [4][32][64] swz
  float*          const x2s = (float*)shmem;                     // [64][132] fp32
  __hip_bfloat16* const hbA = (__hip_bfloat16*)shmem;            // [64][136]
  __hip_bfloat16* const hbB = (__hip_bfloat16*)(shmem + 17408);  // [64][136]

  const int tid = threadIdx.x, wave = tid >> 6, lane = tid & 63;
  const int l15 = lane & 15, quad = lane >> 4;
  const int h = wave >> 1, half = wave & 1;
  const int b = blockIdx.x >> 6, wi = (blockIdx.x >> 3) & 7, wj = blockIdx.x & 7;

  // ---- phase 1: LN1 over source rows (roll -3) -> hbuf bf16 ----
  {
    float g0 = n1g[lane], g1 = n1g[lane+64], e0 = n1b[lane], e1 = n1b[lane+64];
    float va[7], vb[7];
    #pragma unroll
    for (int i = 0; i < 7; ++i) {
      int n = wave + i*8;
      va[i] = 0.f; vb[i] = 0.f;
      if (n < 49) {
        int r = n / 7, c = n - r * 7;
        int si = wi*7 + r + 3; if (si >= 56) si -= 56;
        int sj = wj*7 + c + 3; if (sj >= 56) sj -= 56;
        const float* xr = x + (b*3136 + si*56 + sj) * 128;
        va[i] = xr[lane]; vb[i] = xr[lane + 64];
      }
    }
    #pragma unroll
    for (int i = 0; i < 7; ++i) {
      int n = wave + i*8;
      if (n < 49) {
        float s = va[i] + vb[i], sq = va[i]*va[i] + vb[i]*vb[i];
        #pragma unroll
        for (int off = 32; off > 0; off >>= 1) {
          s  += __shfl_xor(s,  off);
          sq += __shfl_xor(sq, off);
        }
        float mean = s * 0.0078125f;
        float var  = sq * 0.0078125f - mean*mean;
        float rstd = rsqrtf(var + 1e-5f);
        hbuf[n][lane]    = __float2bfloat16((va[i]-mean)*rstd*g0 + e0);
        hbuf[n][lane+64] = __float2bfloat16((vb[i]-mean)*rstd*g1 + e1);
      }
    }
  }
  __syncthreads();   // B1

  // ---- phase 2a: K tile + V tile (one 16-feature tile each per wave) ----
  {
    f32x4 kacc[4] = {}, vacc[4] = {};
    #pragma unroll
    for (int ks = 0; ks < 4; ++ks) {
      short8 hf[4];
      #pragma unroll
      for (int mt = 0; mt < 4; ++mt)
        hf[mt] = *(const short8*)(&hbuf[mt*16 + l15][ks*32 + quad*8]);
      short8 wfk = *(const short8*)(qkvwb + (128 + wave*16 + l15)*128 + ks*32 + quad*8);
      short8 wfv = *(const short8*)(qkvwb + (256 + wave*16 + l15)*128 + ks*32 + quad*8);
      #pragma unroll
      for (int mt = 0; mt < 4; ++mt) {
        kacc[mt] = __builtin_amdgcn_mfma_f32_16x16x32_bf16(wfk, hf[mt], kacc[mt], 0, 0, 0);  // D[f][m]
        vacc[mt] = __builtin_amdgcn_mfma_f32_16x16x32_bf16(hf[mt], wfv, vacc[mt], 0, 0, 0);  // D[m][f]
      }
    }
    // K epilogue -> Kl[hh][m][d0..d0+3] (stride 40, m<49 guard)
    {
      const int fo = wave*16 + quad*4;
      const int hh = wave >> 1, d0 = fo & 31;
      float bb[4];
      #pragma unroll
      for (int r = 0; r < 4; ++r) bb[r] = qkvb[128 + fo + r];
      #pragma unroll
      for (int mt = 0; mt < 4; ++mt) {
        int m = mt*16 + l15;
        if (m < 49) {
          short4v pkv;
          #pragma unroll
          for (int r = 0; r < 4; ++r) pkv[r] = f2bs(kacc[mt][r] + bb[r]);
          *(short4v*)(Kl + (hh*64 + m)*40 + d0) = pkv;
        }
      }
    }
    // V epilogue -> vTl swizzled [hh][d][m], zero-pad m>=49
    {
      const int fv = wave*16 + l15;
      const int hh = wave >> 1, d = fv & 31;
      const float bia = qkvb[256 + fv];
      #pragma unroll
      for (int mt = 0; mt < 4; ++mt) {
        int m0 = mt*16 + quad*4;
        #pragma unroll
        for (int r = 0; r < 4; ++r) {
          int m = m0 + r;
          float v = (m < 49) ? (vacc[mt][r] + bia) : 0.f;
          vTl[(hh*32 + d)*64 + ((((m>>3) ^ (d & 7))) << 3) + (m & 7)] = __float2bfloat16(v);
        }
      }
    }
  }

  // ---- phase 2b: Q (this wave's n-half only) -> register B-fragments ----
  Frag qfr[2];
  {
    f32x4 qacc[2][2] = {};   // [tq][nt], D[f][m] with m-tiles half*2+nt
    #pragma unroll
    for (int ks = 0; ks < 4; ++ks) {
      short8 hfq[2];
      #pragma unroll
      for (int nt = 0; nt < 2; ++nt)
        hfq[nt] = *(const short8*)(&hbuf[(half*2 + nt)*16 + l15][ks*32 + quad*8]);
      #pragma unroll
      for (int tq = 0; tq < 2; ++tq) {
        short8 wf = *(const short8*)(qkvwb + ((h*2 + tq)*16 + l15)*128 + ks*32 + quad*8);
        #pragma unroll
        for (int nt = 0; nt < 2; ++nt)
          qacc[tq][nt] = __builtin_amdgcn_mfma_f32_16x16x32_bf16(wf, hfq[nt], qacc[tq][nt], 0, 0, 0);
      }
    }
    const float qs = 0.17677669529663687f;
    unsigned pkq[2][2][2];
    #pragma unroll
    for (int tq = 0; tq < 2; ++tq) {
      float bb[4];
      #pragma unroll
      for (int r = 0; r < 4; ++r) bb[r] = qkvb[h*32 + tq*16 + quad*4 + r];
      #pragma unroll
      for (int nt = 0; nt < 2; ++nt)
        #pragma unroll
        for (int i = 0; i < 2; ++i) {
          unsigned lo = (unsigned short)f2bs((qacc[tq][nt][2*i]   + bb[2*i])   * qs);
          unsigned hi = (unsigned short)f2bs((qacc[tq][nt][2*i+1] + bb[2*i+1]) * qs);
          pkq[tq][nt][i] = lo | (hi << 16);
        }
    }
    // D[f][m] -> B-frag[n][d]: quad-group exchange (same l15 = token)
    #pragma unroll
    for (int nt = 0; nt < 2; ++nt)
      #pragma unroll
      for (int p = 0; p < 4; ++p) {
        int sl = (((quad & 1)*2 + (p >> 1)) << 4) | l15;
        int a  = __shfl((int)pkq[0][nt][p & 1], sl);
        int c2 = __shfl((int)pkq[1][nt][p & 1], sl);
        qfr[nt].i[p] = (quad >= 2) ? c2 : a;
      }
  }
  __syncthreads();   // B2: K, vT ready

  // ---- phase 3: attention (no internal barrier; Q/P in registers) ----
  {
    short8 kf[4];
    #pragma unroll
    for (int mt = 0; mt < 4; ++mt)
      kf[mt] = *(const short8*)(Kl + (h*64 + mt*16 + l15)*40 + quad*8);

    f32x4 sacc[4][2] = {};   // [mt][nc]: m = mt*16+quad*4+r, n = (half*2+nc)*16+l15
    #pragma unroll
    for (int mt = 0; mt < 4; ++mt)
      #pragma unroll
      for (int nc = 0; nc < 2; ++nc)
        sacc[mt][nc] = __builtin_amdgcn_mfma_f32_16x16x32_bf16(kf[mt], qfr[nc].s, sacc[mt][nc], 0, 0, 0);

    const float* bT = biasT + h*4096;
    #pragma unroll
    for (int mt = 0; mt < 4; ++mt)
      #pragma unroll
      for (int nc = 0; nc < 2; ++nc)
        #pragma unroll
        for (int r = 0; r < 4; ++r)
          sacc[mt][nc][r] += bT[(mt*16 + quad*4 + r)*64 + (half*2 + nc)*16 + l15];

    unsigned pk[4][2][2];
    #pragma unroll
    for (int nc = 0; nc < 2; ++nc) {
      float mx = -1e30f;
      #pragma unroll
      for (int mt = 0; mt < 3; ++mt)
        #pragma unroll
        for (int r = 0; r < 4; ++r) mx = fmaxf(mx, sacc[mt][nc][r]);
      mx = fmaxf(mx, (quad == 0) ? sacc[3][nc][0] : -1e30f);   // m=48 only
      mx = fmaxf(mx, __shfl_xor(mx, 16));
      mx = fmaxf(mx, __shfl_xor(mx, 32));
      float sum = 0.f;
      #pragma unroll
      for (int mt = 0; mt < 3; ++mt)
        #pragma unroll
        for (int r = 0; r < 4; ++r) {
          float e = __expf(sacc[mt][nc][r] - mx);
          sacc[mt][nc][r] = e; sum += e;
        }
      {
        float e = (quad == 0) ? __expf(sacc[3][nc][0] - mx) : 0.f;
        sacc[3][nc][0] = e; sacc[3][nc][1] = 0.f; sacc[3][nc][2] = 0.f; sacc[3][nc][3] = 0.f;
        sum += e;
      }
      sum += __shfl_xor(sum, 16);
      sum += __shfl_xor(sum, 32);
      float inv = 1.f / sum;
      #pragma unroll
      for (int mt = 0; mt < 4; ++mt)
        #pragma unroll
        for (int i = 0; i < 2; ++i) {
          unsigned lo = (unsigned short)f2bs(sacc[mt][nc][2*i]   * inv);
          unsigned hi = (unsigned short)f2bs(sacc[mt][nc][2*i+1] * inv);
          pk[mt][nc][i] = lo | (hi << 16);
        }
    }
    // P: D[m][n] -> B-frag[n][m] in-register (quad-group exchange)
    Frag pfr[2][2];
    #pragma unroll
    for (int kt = 0; kt < 2; ++kt)
      #pragma unroll
      for (int nc = 0; nc < 2; ++nc)
        #pragma unroll
        for (int p = 0; p < 4; ++p) {
          int sl = (((quad & 1)*2 + (p >> 1)) << 4) | l15;
          int a  = __shfl((int)pk[kt*2    ][nc][p & 1], sl);
          int c2 = __shfl((int)pk[kt*2 + 1][nc][p & 1], sl);
          pfr[kt][nc].i[p] = (quad >= 2) ? c2 : a;
        }

    // AV: A=V^T rows d (swizzled vT), B=P rows n -> D[d][n]
    f32x4 oacc[2][2] = {};
    #pragma unroll
    for (int kt = 0; kt < 2; ++kt) {
      short8 vf[2];
      #pragma unroll
      for (int dt = 0; dt < 2; ++dt)
        vf[dt] = *(const short8*)(vTl + (h*32 + dt*16 + l15)*64 + (((kt*4 + quad) ^ (l15 & 7)) << 3));
      #pragma unroll
      for (int dt = 0; dt < 2; ++dt)
        #pragma unroll
        for (int nc = 0; nc < 2; ++nc)
          oacc[dt][nc] = __builtin_amdgcn_mfma_f32_16x16x32_bf16(vf[dt], pfr[kt][nc].s, oacc[dt][nc], 0, 0, 0);
    }
    #pragma unroll
    for (int dt = 0; dt < 2; ++dt)
      #pragma unroll
      for (int nc = 0; nc < 2; ++nc) {
        int n = (half*2 + nc)*16 + l15;
        if (n < 49) {
          short4v pkv;
          #pragma unroll
          for (int r = 0; r < 4; ++r) pkv[r] = f2bs(oacc[dt][nc][r]);
          *(short4v*)(&hbuf[n][h*32 + dt*16 + quad*4]) = pkv;
        }
      }
  }
  __syncthreads();   // B3: hbuf-o ready; K/vT dead -> x2s region free

  // ---- phase 4: proj + shortcut -> x2 in REGISTERS + fp32 x2s (overlay) ----
  f32x4 x2v[4];   // [mt]: m = mt*16+quad*4+r, f = wave*16+l15
  {
    const int n = wave * 16 + l15;
    float xres[4][4];
    #pragma unroll
    for (int mt = 0; mt < 4; ++mt) {
      #pragma unroll
      for (int r = 0; r < 4; ++r) {
        int m = mt*16 + quad*4 + r;
        float v = 0.f;
        if (m < 49) {
          int rr = m / 7, cc = m - rr * 7;
          int si = wi*7 + rr + 3; if (si >= 56) si -= 56;
          int sj = wj*7 + cc + 3; if (sj >= 56) sj -= 56;
          v = x[(b*3136 + si*56 + sj) * 128 + n];
        }
        xres[mt][r] = v;
      }
    }
    f32x4 acc[4] = {};
    #pragma unroll
    for (int ks = 0; ks < 4; ++ks) {
      short8 af[4];
      #pragma unroll
      for (int mt = 0; mt < 4; ++mt)
        af[mt] = *(const short8*)(&hbuf[mt*16 + l15][ks*32 + quad*8]);
      short8 bfr = *(const short8*)(projwb + n*128 + ks*32 + quad*8);
      #pragma unroll
      for (int mt = 0; mt < 4; ++mt)
        acc[mt] = __builtin_amdgcn_mfma_f32_16x16x32_bf16(af[mt], bfr, acc[mt], 0, 0, 0);
    }
    float pbv = projb[n];
    #pragma unroll
    for (int mt = 0; mt < 4; ++mt) {
      #pragma unroll
      for (int r = 0; r < 4; ++r) {
        int m = mt*16 + quad*4 + r;
        float v = 0.f;
        if (m < 49) v = acc[mt][r] + pbv + xres[mt][r];
        x2v[mt][r] = v;
        x2s[m*132 + n] = v;
      }
    }
  }
  __syncthreads();   // B4: x2s ready

  // ---- phase 5: LN2 from x2s -> hbuf bf16 ----
  {
    float g0 = n2g[lane], g1 = n2g[lane+64], e0 = n2b[lane], e1 = n2b[lane+64];
    for (int n = wave; n < 49; n += 8) {
      float v0 = x2s[n*132 + lane], v1 = x2s[n*132 + lane + 64];
      float s = v0 + v1, sq = v0*v0 + v1*v1;
      #pragma unroll
      for (int off = 32; off > 0; off >>= 1) {
        s  += __shfl_xor(s,  off);
        sq += __shfl_xor(sq, off);
      }
      float mean = s * 0.0078125f;
      float var  = sq * 0.0078125f - mean*mean;
      float rstd = rsqrtf(var + 1e-5f);
      hbuf[n][lane]    = __float2bfloat16((v0-mean)*rstd*g0 + e0);
      hbuf[n][lane+64] = __float2bfloat16((v1-mean)*rstd*g1 + e1);
    }
    __hip_bfloat16 z = __float2bfloat16(0.f);
    for (int n = 49 + wave; n < 64; n += 8) {   // zero pad rows for GEMM1
      hbuf[n][lane] = z; hbuf[n][lane+64] = z;
    }
  }
  __syncthreads();   // B5: ln ready; x2s dead -> hb dbuf region free

  // ---- phase 6: MLP, hidden in 4 chunks of 128, double-buffered ----
  f32x4 acc2[4] = {};   // [mt]: m = mt*16+quad*4+r, f = wave*16+l15
  const int fb2 = wave * 16;

  auto G1 = [&](int c, __hip_bfloat16* dst) {
    const int jg = c*128 + wave*16;
    f32x4 a1[4] = {};
    #pragma unroll
    for (int ks = 0; ks < 4; ++ks) {
      short8 lf[4];
      #pragma unroll
      for (int mt = 0; mt < 4; ++mt)
        lf[mt] = *(const short8*)(&hbuf[mt*16 + l15][ks*32 + quad*8]);
      short8 wf = *(const short8*)(w1b + (jg + l15)*128 + ks*32 + quad*8);
      #pragma unroll
      for (int mt = 0; mt < 4; ++mt)
        a1[mt] = __builtin_amdgcn_mfma_f32_16x16x32_bf16(wf, lf[mt], a1[mt], 0, 0, 0);  // D[j][m]
    }
    float bb[4];
    #pragma unroll
    for (int r = 0; r < 4; ++r) bb[r] = b1[jg + quad*4 + r];
    #pragma unroll
    for (int mt = 0; mt < 4; ++mt) {
      int m = mt*16 + l15;
      short4v pkv;
      #pragma unroll
      for (int r = 0; r < 4; ++r) pkv[r] = f2bs(gelu_f(a1[mt][r] + bb[r]));
      *(short4v*)(dst + m*136 + wave*16 + quad*4) = pkv;
    }
  };
  auto G2 = [&](int c, const __hip_bfloat16* src) {
    #pragma unroll
    for (int ks = 0; ks < 4; ++ks) {
      short8 af[4];
      #pragma unroll
      for (int mt = 0; mt < 4; ++mt)
        af[mt] = *(const short8*)(src + (mt*16 + l15)*136 + ks*32 + quad*8);
      short8 wf = *(const short8*)(w2b + (fb2 + l15)*512 + c*128 + ks*32 + quad*8);
      #pragma unroll
      for (int mt = 0; mt < 4; ++mt)
        acc2[mt] = __builtin_amdgcn_mfma_f32_16x16x32_bf16(af[mt], wf, acc2[mt], 0, 0, 0);
    }
  };

  G1(0, hbA);
  __syncthreads();            // B6
  G1(1, hbB); G2(0, hbA);
  __syncthreads();            // B7
  G1(2, hbA); G2(1, hbB);
  __syncthreads();            // B8
  G1(3, hbB); G2(2, hbA);
  __syncthreads();            // B9
  G2(3, hbB);

  // ---- epilogue: bias + register residual, scatter (roll +3) ----
  {
    const int f = fb2 + l15;
    const float bb = b2[f];
    #pragma unroll
    for (int mt = 0; mt < 4; ++mt) {
      #pragma unroll
      for (int r = 0; r < 4; ++r) {
        int m = mt*16 + quad*4 + r;
        if (m < 49) {
          int rr = m / 7, cc = m - rr * 7;
          int si = wi*7 + rr + 3; if (si >= 56) si -= 56;
          int sj = wj*7 + cc + 3; if (sj >= 56) sj -= 56;
          int o = (b*3136 + si*56 + sj) * 128 + f;
          out[o] = acc2[mt][r] + bb + x2v[mt][r];
        }
      }
    }
  }
}

extern "C" void kernel_launch(void* const* d_in, const int* in_sizes, int n_in,
                              void* d_out, int out_size, void* d_ws, size_t ws_size,
                              hipStream_t stream) {
  const float* x     = (const float*)d_in[0];
  const float* n1g   = (const float*)d_in[3];
  const float* n1b   = (const float*)d_in[4];
  const float* qkvw  = (const float*)d_in[5];
  const float* qkvb  = (const float*)d_in[6];
  const float* tab   = (const float*)d_in[7];
  const int*   ridx  = (const int*)d_in[8];
  const float* projw = (const float*)d_in[9];
  const float* projb = (const float*)d_in[10];
  const float* n2g   = (const float*)d_in[11];
  const float* n2b   = (const float*)d_in[12];
  const float* w1    = (const float*)d_in[13];
  const float* b1    = (const float*)d_in[14];
  const float* w2    = (const float*)d_in[15];
  const float* b2    = (const float*)d_in[16];
  float* outp = (float*)d_out;

  __hip_bfloat16* wsb = (__hip_bfloat16*)d_ws;
  float* biasT = (float*)((char*)d_ws + BIAS_BYTE_OFF);

  hipLaunchKernelGGL(conv_kernel, dim3(832), dim3(256), 0, stream,
                     qkvw, projw, w1, w2, tab, ridx, wsb, biasT);
  hipLaunchKernelGGL(fused_kernel, dim3(NWIN), dim3(512), 0, stream,
                     x, n1g, n1b, wsb + QKVW_OFF, qkvb, biasT, wsb + PROJW_OFF, projb,
                     n2g, n2b, wsb + W1_OFF, b1, wsb + W2_OFF, b2, outp);
}

// Round 7
// 259.114 us; speedup vs baseline: 1.1766x; 1.1766x over previous
//
#include <hip/hip_runtime.h>
#include <hip/hip_bf16.h>

// Swin block, B=32 H=W=56 C=128, ws=7 (N=49), nh=4 (hd=32), shift=3, hid=512.
// fp32 in/out. All GEMMs AND attention (QK^T, AV) via mfma_f32_16x16x32_bf16.
// roll(-3) gather == roll(+3) scatter target -> fully fused windows.
// R12: R11 (LDS 54272 B: reg-resident Q/P via quad-group shuffle transpose,
//     swizzled vT, x2s + dbuf MLP overlays) but with __launch_bounds__(512,4)
//     instead of (512,6). R11's forced 6-waves/EU drove the allocator to a
//     40-VGPR tier with catastrophic scratch spill (FETCH/WRITE 3x, 234us).
//     At (512,4) the compiler naturally squeezes to the 64-VGPR tier (proven
//     R7-R10), giving blocks/CU = min(LDS: 163840/54272=3, VGPR: 4) = 3
//     -> 24 waves/CU vs R10's 16, with zero spill.

#define NWIN 2048

typedef short short8  __attribute__((ext_vector_type(8)));
typedef short short4v __attribute__((ext_vector_type(4)));
typedef float f32x4   __attribute__((ext_vector_type(4)));

union Frag { int i[4]; unsigned u[4]; short8 s; };

#define QKVW_OFF  0        // 384*128 bf16
#define PROJW_OFF 49152    // 128*128
#define W1_OFF    65536    // 512*128
#define W2_OFF    131072   // 128*512
#define BIAS_BYTE_OFF 393216  // biasT[4][64][64] fp32 (padded, 0 outside 49x49)

__device__ __forceinline__ short f2bs(float v) {
  __hip_bfloat16 h = __float2bfloat16(v);
  union { __hip_bfloat16 h; short s; } u; u.h = h; return u.s;
}
__device__ __forceinline__ float gelu_f(float v) {
  float u = v * (0.7978845608028654f + 0.03567740814f * v * v);
  return v * __builtin_amdgcn_rcpf(1.f + __expf(-2.f * u));
}

// ---------------- pre-pass: weights -> bf16, padded bias^T gather ----------------
__global__ __launch_bounds__(256) void conv_kernel(
    const float* __restrict__ qkvw, const float* __restrict__ projw,
    const float* __restrict__ w1,   const float* __restrict__ w2,
    const float* __restrict__ tab,  const int* __restrict__ ridx,
    __hip_bfloat16* __restrict__ wsb, float* __restrict__ biasT)
{
  int idx = blockIdx.x * 256 + threadIdx.x;
  if (idx < 49152)       wsb[QKVW_OFF + idx]          = __float2bfloat16(qkvw[idx]);
  else if (idx < 65536)  wsb[PROJW_OFF + idx - 49152] = __float2bfloat16(projw[idx - 49152]);
  else if (idx < 131072) wsb[W1_OFF + idx - 65536]    = __float2bfloat16(w1[idx - 65536]);
  else if (idx < 196608) wsb[W2_OFF + idx - 131072]   = __float2bfloat16(w2[idx - 131072]);
  else if (idx < 212992) {
    int i = idx - 196608;
    int h = i >> 12, m = (i >> 6) & 63, n = i & 63;   // biasT[h][m=key][n=query]
    biasT[i] = (m < 49 && n < 49) ? tab[ridx[n*49 + m]*4 + h] : 0.f;
  }
}

// ------- fused: LN1 + window attn + proj + shortcut + LN2 + MLP + residual -------
__global__ __launch_bounds__(512, 4) void fused_kernel(
    const float* __restrict__ x,
    const float* __restrict__ n1g, const float* __restrict__ n1b,
    const __hip_bfloat16* __restrict__ qkvwb, const float* __restrict__ qkvb,
    const float* __restrict__ biasT,
    const __hip_bfloat16* __restrict__ projwb, const float* __restrict__ projb,
    const float* __restrict__ n2g, const float* __restrict__ n2b,
    const __hip_bfloat16* __restrict__ w1b, const float* __restrict__ b1,
    const __hip_bfloat16* __restrict__ w2b, const float* __restrict__ b2,
    float* __restrict__ out)
{
  __shared__ alignas(16) __hip_bfloat16 hbuf[64][136];   // 17408 B: h / o / ln2
  __shared__ alignas(16) char shmem[36864];              // K+vT | x2s | hb dbuf
  __hip_bfloat16* const Kl  = (__hip_bfloat16*)shmem;            // [4][64][40]
  __hip_bfloat16* const vTl = (__hip_bfloat16*)(shmem + 20480);  // [4][32][64] swz
  float*          const x2s = (float*)shmem;                     // [64][132] fp32
  __hip_bfloat16* const hbA = (__hip_bfloat16*)shmem;            // [64][136]
  __hip_bfloat16* const hbB = (__hip_bfloat16*)(shmem + 17408);  // [64][136]

  const int tid = threadIdx.x, wave = tid >> 6, lane = tid & 63;
  const int l15 = lane & 15, quad = lane >> 4;
  const int h = wave >> 1, half = wave & 1;
  const int b = blockIdx.x >> 6, wi = (blockIdx.x >> 3) & 7, wj = blockIdx.x & 7;

  // ---- phase 1: LN1 over source rows (roll -3) -> hbuf bf16 ----
  {
    float g0 = n1g[lane], g1 = n1g[lane+64], e0 = n1b[lane], e1 = n1b[lane+64];
    float va[7], vb[7];
    #pragma unroll
    for (int i = 0; i < 7; ++i) {
      int n = wave + i*8;
      va[i] = 0.f; vb[i] = 0.f;
      if (n < 49) {
        int r = n / 7, c = n - r * 7;
        int si = wi*7 + r + 3; if (si >= 56) si -= 56;
        int sj = wj*7 + c + 3; if (sj >= 56) sj -= 56;
        const float* xr = x + (b*3136 + si*56 + sj) * 128;
        va[i] = xr[lane]; vb[i] = xr[lane + 64];
      }
    }
    #pragma unroll
    for (int i = 0; i < 7; ++i) {
      int n = wave + i*8;
      if (n < 49) {
        float s = va[i] + vb[i], sq = va[i]*va[i] + vb[i]*vb[i];
        #pragma unroll
        for (int off = 32; off > 0; off >>= 1) {
          s  += __shfl_xor(s,  off);
          sq += __shfl_xor(sq, off);
        }
        float mean = s * 0.0078125f;
        float var  = sq * 0.0078125f - mean*mean;
        float rstd = rsqrtf(var + 1e-5f);
        hbuf[n][lane]    = __float2bfloat16((va[i]-mean)*rstd*g0 + e0);
        hbuf[n][lane+64] = __float2bfloat16((vb[i]-mean)*rstd*g1 + e1);
      }
    }
  }
  __syncthreads();   // B1

  // ---- phase 2a: K tile + V tile (one 16-feature tile each per wave) ----
  {
    f32x4 kacc[4] = {}, vacc[4] = {};
    #pragma unroll
    for (int ks = 0; ks < 4; ++ks) {
      short8 hf[4];
      #pragma unroll
      for (int mt = 0; mt < 4; ++mt)
        hf[mt] = *(const short8*)(&hbuf[mt*16 + l15][ks*32 + quad*8]);
      short8 wfk = *(const short8*)(qkvwb + (128 + wave*16 + l15)*128 + ks*32 + quad*8);
      short8 wfv = *(const short8*)(qkvwb + (256 + wave*16 + l15)*128 + ks*32 + quad*8);
      #pragma unroll
      for (int mt = 0; mt < 4; ++mt) {
        kacc[mt] = __builtin_amdgcn_mfma_f32_16x16x32_bf16(wfk, hf[mt], kacc[mt], 0, 0, 0);  // D[f][m]
        vacc[mt] = __builtin_amdgcn_mfma_f32_16x16x32_bf16(hf[mt], wfv, vacc[mt], 0, 0, 0);  // D[m][f]
      }
    }
    // K epilogue -> Kl[hh][m][d0..d0+3] (stride 40, m<49 guard)
    {
      const int fo = wave*16 + quad*4;
      const int hh = wave >> 1, d0 = fo & 31;
      float bb[4];
      #pragma unroll
      for (int r = 0; r < 4; ++r) bb[r] = qkvb[128 + fo + r];
      #pragma unroll
      for (int mt = 0; mt < 4; ++mt) {
        int m = mt*16 + l15;
        if (m < 49) {
          short4v pkv;
          #pragma unroll
          for (int r = 0; r < 4; ++r) pkv[r] = f2bs(kacc[mt][r] + bb[r]);
          *(short4v*)(Kl + (hh*64 + m)*40 + d0) = pkv;
        }
      }
    }
    // V epilogue -> vTl swizzled [hh][d][m], zero-pad m>=49
    {
      const int fv = wave*16 + l15;
      const int hh = wave >> 1, d = fv & 31;
      const float bia = qkvb[256 + fv];
      #pragma unroll
      for (int mt = 0; mt < 4; ++mt) {
        int m0 = mt*16 + quad*4;
        #pragma unroll
        for (int r = 0; r < 4; ++r) {
          int m = m0 + r;
          float v = (m < 49) ? (vacc[mt][r] + bia) : 0.f;
          vTl[(hh*32 + d)*64 + ((((m>>3) ^ (d & 7))) << 3) + (m & 7)] = __float2bfloat16(v);
        }
      }
    }
  }

  // ---- phase 2b: Q (this wave's n-half only) -> register B-fragments ----
  Frag qfr[2];
  {
    f32x4 qacc[2][2] = {};   // [tq][nt], D[f][m] with m-tiles half*2+nt
    #pragma unroll
    for (int ks = 0; ks < 4; ++ks) {
      short8 hfq[2];
      #pragma unroll
      for (int nt = 0; nt < 2; ++nt)
        hfq[nt] = *(const short8*)(&hbuf[(half*2 + nt)*16 + l15][ks*32 + quad*8]);
      #pragma unroll
      for (int tq = 0; tq < 2; ++tq) {
        short8 wf = *(const short8*)(qkvwb + ((h*2 + tq)*16 + l15)*128 + ks*32 + quad*8);
        #pragma unroll
        for (int nt = 0; nt < 2; ++nt)
          qacc[tq][nt] = __builtin_amdgcn_mfma_f32_16x16x32_bf16(wf, hfq[nt], qacc[tq][nt], 0, 0, 0);
      }
    }
    const float qs = 0.17677669529663687f;
    unsigned pkq[2][2][2];
    #pragma unroll
    for (int tq = 0; tq < 2; ++tq) {
      float bb[4];
      #pragma unroll
      for (int r = 0; r < 4; ++r) bb[r] = qkvb[h*32 + tq*16 + quad*4 + r];
      #pragma unroll
      for (int nt = 0; nt < 2; ++nt)
        #pragma unroll
        for (int i = 0; i < 2; ++i) {
          unsigned lo = (unsigned short)f2bs((qacc[tq][nt][2*i]   + bb[2*i])   * qs);
          unsigned hi = (unsigned short)f2bs((qacc[tq][nt][2*i+1] + bb[2*i+1]) * qs);
          pkq[tq][nt][i] = lo | (hi << 16);
        }
    }
    // D[f][m] -> B-frag[n][d]: quad-group exchange (same l15 = token)
    #pragma unroll
    for (int nt = 0; nt < 2; ++nt)
      #pragma unroll
      for (int p = 0; p < 4; ++p) {
        int sl = (((quad & 1)*2 + (p >> 1)) << 4) | l15;
        int a  = __shfl((int)pkq[0][nt][p & 1], sl);
        int c2 = __shfl((int)pkq[1][nt][p & 1], sl);
        qfr[nt].i[p] = (quad >= 2) ? c2 : a;
      }
  }
  __syncthreads();   // B2: K, vT ready

  // ---- phase 3: attention (no internal barrier; Q/P in registers) ----
  {
    short8 kf[4];
    #pragma unroll
    for (int mt = 0; mt < 4; ++mt)
      kf[mt] = *(const short8*)(Kl + (h*64 + mt*16 + l15)*40 + quad*8);

    f32x4 sacc[4][2] = {};   // [mt][nc]: m = mt*16+quad*4+r, n = (half*2+nc)*16+l15
    #pragma unroll
    for (int mt = 0; mt < 4; ++mt)
      #pragma unroll
      for (int nc = 0; nc < 2; ++nc)
        sacc[mt][nc] = __builtin_amdgcn_mfma_f32_16x16x32_bf16(kf[mt], qfr[nc].s, sacc[mt][nc], 0, 0, 0);

    const float* bT = biasT + h*4096;
    #pragma unroll
    for (int mt = 0; mt < 4; ++mt)
      #pragma unroll
      for (int nc = 0; nc < 2; ++nc)
        #pragma unroll
        for (int r = 0; r < 4; ++r)
          sacc[mt][nc][r] += bT[(mt*16 + quad*4 + r)*64 + (half*2 + nc)*16 + l15];

    unsigned pk[4][2][2];
    #pragma unroll
    for (int nc = 0; nc < 2; ++nc) {
      float mx = -1e30f;
      #pragma unroll
      for (int mt = 0; mt < 3; ++mt)
        #pragma unroll
        for (int r = 0; r < 4; ++r) mx = fmaxf(mx, sacc[mt][nc][r]);
      mx = fmaxf(mx, (quad == 0) ? sacc[3][nc][0] : -1e30f);   // m=48 only
      mx = fmaxf(mx, __shfl_xor(mx, 16));
      mx = fmaxf(mx, __shfl_xor(mx, 32));
      float sum = 0.f;
      #pragma unroll
      for (int mt = 0; mt < 3; ++mt)
        #pragma unroll
        for (int r = 0; r < 4; ++r) {
          float e = __expf(sacc[mt][nc][r] - mx);
          sacc[mt][nc][r] = e; sum += e;
        }
      {
        float e = (quad == 0) ? __expf(sacc[3][nc][0] - mx) : 0.f;
        sacc[3][nc][0] = e; sacc[3][nc][1] = 0.f; sacc[3][nc][2] = 0.f; sacc[3][nc][3] = 0.f;
        sum += e;
      }
      sum += __shfl_xor(sum, 16);
      sum += __shfl_xor(sum, 32);
      float inv = 1.f / sum;
      #pragma unroll
      for (int mt = 0; mt < 4; ++mt)
        #pragma unroll
        for (int i = 0; i < 2; ++i) {
          unsigned lo = (unsigned short)f2bs(sacc[mt][nc][2*i]   * inv);
          unsigned hi = (unsigned short)f2bs(sacc[mt][nc][2*i+1] * inv);
          pk[mt][nc][i] = lo | (hi << 16);
        }
    }
    // P: D[m][n] -> B-frag[n][m] in-register (quad-group exchange)
    Frag pfr[2][2];
    #pragma unroll
    for (int kt = 0; kt < 2; ++kt)
      #pragma unroll
      for (int nc = 0; nc < 2; ++nc)
        #pragma unroll
        for (int p = 0; p < 4; ++p) {
          int sl = (((quad & 1)*2 + (p >> 1)) << 4) | l15;
          int a  = __shfl((int)pk[kt*2    ][nc][p & 1], sl);
          int c2 = __shfl((int)pk[kt*2 + 1][nc][p & 1], sl);
          pfr[kt][nc].i[p] = (quad >= 2) ? c2 : a;
        }

    // AV: A=V^T rows d (swizzled vT), B=P rows n -> D[d][n]
    f32x4 oacc[2][2] = {};
    #pragma unroll
    for (int kt = 0; kt < 2; ++kt) {
      short8 vf[2];
      #pragma unroll
      for (int dt = 0; dt < 2; ++dt)
        vf[dt] = *(const short8*)(vTl + (h*32 + dt*16 + l15)*64 + (((kt*4 + quad) ^ (l15 & 7)) << 3));
      #pragma unroll
      for (int dt = 0; dt < 2; ++dt)
        #pragma unroll
        for (int nc = 0; nc < 2; ++nc)
          oacc[dt][nc] = __builtin_amdgcn_mfma_f32_16x16x32_bf16(vf[dt], pfr[kt][nc].s, oacc[dt][nc], 0, 0, 0);
    }
    #pragma unroll
    for (int dt = 0; dt < 2; ++dt)
      #pragma unroll
      for (int nc = 0; nc < 2; ++nc) {
        int n = (half*2 + nc)*16 + l15;
        if (n < 49) {
          short4v pkv;
          #pragma unroll
          for (int r = 0; r < 4; ++r) pkv[r] = f2bs(oacc[dt][nc][r]);
          *(short4v*)(&hbuf[n][h*32 + dt*16 + quad*4]) = pkv;
        }
      }
  }
  __syncthreads();   // B3: hbuf-o ready; K/vT dead -> x2s region free

  // ---- phase 4: proj + shortcut -> x2 in REGISTERS + fp32 x2s (overlay) ----
  f32x4 x2v[4];   // [mt]: m = mt*16+quad*4+r, f = wave*16+l15
  {
    const int n = wave * 16 + l15;
    float xres[4][4];
    #pragma unroll
    for (int mt = 0; mt < 4; ++mt) {
      #pragma unroll
      for (int r = 0; r < 4; ++r) {
        int m = mt*16 + quad*4 + r;
        float v = 0.f;
        if (m < 49) {
          int rr = m / 7, cc = m - rr * 7;
          int si = wi*7 + rr + 3; if (si >= 56) si -= 56;
          int sj = wj*7 + cc + 3; if (sj >= 56) sj -= 56;
          v = x[(b*3136 + si*56 + sj) * 128 + n];
        }
        xres[mt][r] = v;
      }
    }
    f32x4 acc[4] = {};
    #pragma unroll
    for (int ks = 0; ks < 4; ++ks) {
      short8 af[4];
      #pragma unroll
      for (int mt = 0; mt < 4; ++mt)
        af[mt] = *(const short8*)(&hbuf[mt*16 + l15][ks*32 + quad*8]);
      short8 bfr = *(const short8*)(projwb + n*128 + ks*32 + quad*8);
      #pragma unroll
      for (int mt = 0; mt < 4; ++mt)
        acc[mt] = __builtin_amdgcn_mfma_f32_16x16x32_bf16(af[mt], bfr, acc[mt], 0, 0, 0);
    }
    float pbv = projb[n];
    #pragma unroll
    for (int mt = 0; mt < 4; ++mt) {
      #pragma unroll
      for (int r = 0; r < 4; ++r) {
        int m = mt*16 + quad*4 + r;
        float v = 0.f;
        if (m < 49) v = acc[mt][r] + pbv + xres[mt][r];
        x2v[mt][r] = v;
        x2s[m*132 + n] = v;
      }
    }
  }
  __syncthreads();   // B4: x2s ready

  // ---- phase 5: LN2 from x2s -> hbuf bf16 ----
  {
    float g0 = n2g[lane], g1 = n2g[lane+64], e0 = n2b[lane], e1 = n2b[lane+64];
    for (int n = wave; n < 49; n += 8) {
      float v0 = x2s[n*132 + lane], v1 = x2s[n*132 + lane + 64];
      float s = v0 + v1, sq = v0*v0 + v1*v1;
      #pragma unroll
      for (int off = 32; off > 0; off >>= 1) {
        s  += __shfl_xor(s,  off);
        sq += __shfl_xor(sq, off);
      }
      float mean = s * 0.0078125f;
      float var  = sq * 0.0078125f - mean*mean;
      float rstd = rsqrtf(var + 1e-5f);
      hbuf[n][lane]    = __float2bfloat16((v0-mean)*rstd*g0 + e0);
      hbuf[n][lane+64] = __float2bfloat16((v1-mean)*rstd*g1 + e1);
    }
    __hip_bfloat16 z = __float2bfloat16(0.f);
    for (int n = 49 + wave; n < 64; n += 8) {   // zero pad rows for GEMM1
      hbuf[n][lane] = z; hbuf[n][lane+64] = z;
    }
  }
  __syncthreads();   // B5: ln ready; x2s dead -> hb dbuf region free

  // ---- phase 6: MLP, hidden in 4 chunks of 128, double-buffered ----
  f32x4 acc2[4] = {};   // [mt]: m = mt*16+quad*4+r, f = wave*16+l15
  const int fb2 = wave * 16;

  auto G1 = [&](int c, __hip_bfloat16* dst) {
    const int jg = c*128 + wave*16;
    f32x4 a1[4] = {};
    #pragma unroll
    for (int ks = 0; ks < 4; ++ks) {
      short8 lf[4];
      #pragma unroll
      for (int mt = 0; mt < 4; ++mt)
        lf[mt] = *(const short8*)(&hbuf[mt*16 + l15][ks*32 + quad*8]);
      short8 wf = *(const short8*)(w1b + (jg + l15)*128 + ks*32 + quad*8);
      #pragma unroll
      for (int mt = 0; mt < 4; ++mt)
        a1[mt] = __builtin_amdgcn_mfma_f32_16x16x32_bf16(wf, lf[mt], a1[mt], 0, 0, 0);  // D[j][m]
    }
    float bb[4];
    #pragma unroll
    for (int r = 0; r < 4; ++r) bb[r] = b1[jg + quad*4 + r];
    #pragma unroll
    for (int mt = 0; mt < 4; ++mt) {
      int m = mt*16 + l15;
      short4v pkv;
      #pragma unroll
      for (int r = 0; r < 4; ++r) pkv[r] = f2bs(gelu_f(a1[mt][r] + bb[r]));
      *(short4v*)(dst + m*136 + wave*16 + quad*4) = pkv;
    }
  };
  auto G2 = [&](int c, const __hip_bfloat16* src) {
    #pragma unroll
    for (int ks = 0; ks < 4; ++ks) {
      short8 af[4];
      #pragma unroll
      for (int mt = 0; mt < 4; ++mt)
        af[mt] = *(const short8*)(src + (mt*16 + l15)*136 + ks*32 + quad*8);
      short8 wf = *(const short8*)(w2b + (fb2 + l15)*512 + c*128 + ks*32 + quad*8);
      #pragma unroll
      for (int mt = 0; mt < 4; ++mt)
        acc2[mt] = __builtin_amdgcn_mfma_f32_16x16x32_bf16(af[mt], wf, acc2[mt], 0, 0, 0);
    }
  };

  G1(0, hbA);
  __syncthreads();            // B6
  G1(1, hbB); G2(0, hbA);
  __syncthreads();            // B7
  G1(2, hbA); G2(1, hbB);
  __syncthreads();            // B8
  G1(3, hbB); G2(2, hbA);
  __syncthreads();            // B9
  G2(3, hbB);

  // ---- epilogue: bias + register residual, scatter (roll +3) ----
  {
    const int f = fb2 + l15;
    const float bb = b2[f];
    #pragma unroll
    for (int mt = 0; mt < 4; ++mt) {
      #pragma unroll
      for (int r = 0; r < 4; ++r) {
        int m = mt*16 + quad*4 + r;
        if (m < 49) {
          int rr = m / 7, cc = m - rr * 7;
          int si = wi*7 + rr + 3; if (si >= 56) si -= 56;
          int sj = wj*7 + cc + 3; if (sj >= 56) sj -= 56;
          int o = (b*3136 + si*56 + sj) * 128 + f;
          out[o] = acc2[mt][r] + bb + x2v[mt][r];
        }
      }
    }
  }
}

extern "C" void kernel_launch(void* const* d_in, const int* in_sizes, int n_in,
                              void* d_out, int out_size, void* d_ws, size_t ws_size,
                              hipStream_t stream) {
  const float* x     = (const float*)d_in[0];
  const float* n1g   = (const float*)d_in[3];
  const float* n1b   = (const float*)d_in[4];
  const float* qkvw  = (const float*)d_in[5];
  const float* qkvb  = (const float*)d_in[6];
  const float* tab   = (const float*)d_in[7];
  const int*   ridx  = (const int*)d_in[8];
  const float* projw = (const float*)d_in[9];
  const float* projb = (const float*)d_in[10];
  const float* n2g   = (const float*)d_in[11];
  const float* n2b   = (const float*)d_in[12];
  const float* w1    = (const float*)d_in[13];
  const float* b1    = (const float*)d_in[14];
  const float* w2    = (const float*)d_in[15];
  const float* b2    = (const float*)d_in[16];
  float* outp = (float*)d_out;

  __hip_bfloat16* wsb = (__hip_bfloat16*)d_ws;
  float* biasT = (float*)((char*)d_ws + BIAS_BYTE_OFF);

  hipLaunchKernelGGL(conv_kernel, dim3(832), dim3(256), 0, stream,
                     qkvw, projw, w1, w2, tab, ridx, wsb, biasT);
  hipLaunchKernelGGL(fused_kernel, dim3(NWIN), dim3(512), 0, stream,
                     x, n1g, n1b, wsb + QKVW_OFF, qkvb, biasT, wsb + PROJW_OFF, projb,
                     n2g, n2b, wsb + W1_OFF, b1, wsb + W2_OFF, b2, outp);
}

// Round 8
// 256.267 us; speedup vs baseline: 1.1897x; 1.0111x over previous
//
#include <hip/hip_runtime.h>
#include <hip/hip_bf16.h>

// Swin block, B=32 H=W=56 C=128, ws=7 (N=49), nh=4 (hd=32), shift=3, hid=512.
// fp32 in/out. All GEMMs AND attention (QK^T, AV) via mfma_f32_16x16x32_bf16.
// roll(-3) gather == roll(+3) scatter target -> fully fused windows.
// R13: R12 failed to reach 3 blocks/CU: 3x54272=162816 vs 163840 pool -- a
//     1KB margin eaten by runtime LDS reserve/padding (occupancy stayed 42%,
//     dur identical to R10). Cut K from per-head [4][64][40] (20480B) to
//     token-major [64][136] (17408B, hbuf's proven stride/conflict pattern).
//     Total LDS 54272 -> 52224; 3x52224 = 156672 (7KB slack) -> 3 blocks/CU.
//     Everything else identical to R12 (one-variable residency experiment).

#define NWIN 2048

typedef short short8  __attribute__((ext_vector_type(8)));
typedef short short4v __attribute__((ext_vector_type(4)));
typedef float f32x4   __attribute__((ext_vector_type(4)));

union Frag { int i[4]; unsigned u[4]; short8 s; };

#define QKVW_OFF  0        // 384*128 bf16
#define PROJW_OFF 49152    // 128*128
#define W1_OFF    65536    // 512*128
#define W2_OFF    131072   // 128*512
#define BIAS_BYTE_OFF 393216  // biasT[4][64][64] fp32 (padded, 0 outside 49x49)

__device__ __forceinline__ short f2bs(float v) {
  __hip_bfloat16 h = __float2bfloat16(v);
  union { __hip_bfloat16 h; short s; } u; u.h = h; return u.s;
}
__device__ __forceinline__ float gelu_f(float v) {
  float u = v * (0.7978845608028654f + 0.03567740814f * v * v);
  return v * __builtin_amdgcn_rcpf(1.f + __expf(-2.f * u));
}

// ---------------- pre-pass: weights -> bf16, padded bias^T gather ----------------
__global__ __launch_bounds__(256) void conv_kernel(
    const float* __restrict__ qkvw, const float* __restrict__ projw,
    const float* __restrict__ w1,   const float* __restrict__ w2,
    const float* __restrict__ tab,  const int* __restrict__ ridx,
    __hip_bfloat16* __restrict__ wsb, float* __restrict__ biasT)
{
  int idx = blockIdx.x * 256 + threadIdx.x;
  if (idx < 49152)       wsb[QKVW_OFF + idx]          = __float2bfloat16(qkvw[idx]);
  else if (idx < 65536)  wsb[PROJW_OFF + idx - 49152] = __float2bfloat16(projw[idx - 49152]);
  else if (idx < 131072) wsb[W1_OFF + idx - 65536]    = __float2bfloat16(w1[idx - 65536]);
  else if (idx < 196608) wsb[W2_OFF + idx - 131072]   = __float2bfloat16(w2[idx - 131072]);
  else if (idx < 212992) {
    int i = idx - 196608;
    int h = i >> 12, m = (i >> 6) & 63, n = i & 63;   // biasT[h][m=key][n=query]
    biasT[i] = (m < 49 && n < 49) ? tab[ridx[n*49 + m]*4 + h] : 0.f;
  }
}

// ------- fused: LN1 + window attn + proj + shortcut + LN2 + MLP + residual -------
__global__ __launch_bounds__(512, 4) void fused_kernel(
    const float* __restrict__ x,
    const float* __restrict__ n1g, const float* __restrict__ n1b,
    const __hip_bfloat16* __restrict__ qkvwb, const float* __restrict__ qkvb,
    const float* __restrict__ biasT,
    const __hip_bfloat16* __restrict__ projwb, const float* __restrict__ projb,
    const float* __restrict__ n2g, const float* __restrict__ n2b,
    const __hip_bfloat16* __restrict__ w1b, const float* __restrict__ b1,
    const __hip_bfloat16* __restrict__ w2b, const float* __restrict__ b2,
    float* __restrict__ out)
{
  __shared__ alignas(16) __hip_bfloat16 hbuf[64][136];   // 17408 B: h / o / ln2
  __shared__ alignas(16) char shmem[34816];              // K+vT | x2s | hb dbuf
  __hip_bfloat16* const Kl  = (__hip_bfloat16*)shmem;            // [64][136] token-major
  __hip_bfloat16* const vTl = (__hip_bfloat16*)(shmem + 17408);  // [4][32][64] swz
  float*          const x2s = (float*)shmem;                     // [64][132] fp32
  __hip_bfloat16* const hbA = (__hip_bfloat16*)shmem;            // [64][136]
  __hip_bfloat16* const hbB = (__hip_bfloat16*)(shmem + 17408);  // [64][136]

  const int tid = threadIdx.x, wave = tid >> 6, lane = tid & 63;
  const int l15 = lane & 15, quad = lane >> 4;
  const int h = wave >> 1, half = wave & 1;
  const int b = blockIdx.x >> 6, wi = (blockIdx.x >> 3) & 7, wj = blockIdx.x & 7;

  // ---- phase 1: LN1 over source rows (roll -3) -> hbuf bf16 ----
  {
    float g0 = n1g[lane], g1 = n1g[lane+64], e0 = n1b[lane], e1 = n1b[lane+64];
    float va[7], vb[7];
    #pragma unroll
    for (int i = 0; i < 7; ++i) {
      int n = wave + i*8;
      va[i] = 0.f; vb[i] = 0.f;
      if (n < 49) {
        int r = n / 7, c = n - r * 7;
        int si = wi*7 + r + 3; if (si >= 56) si -= 56;
        int sj = wj*7 + c + 3; if (sj >= 56) sj -= 56;
        const float* xr = x + (b*3136 + si*56 + sj) * 128;
        va[i] = xr[lane]; vb[i] = xr[lane + 64];
      }
    }
    #pragma unroll
    for (int i = 0; i < 7; ++i) {
      int n = wave + i*8;
      if (n < 49) {
        float s = va[i] + vb[i], sq = va[i]*va[i] + vb[i]*vb[i];
        #pragma unroll
        for (int off = 32; off > 0; off >>= 1) {
          s  += __shfl_xor(s,  off);
          sq += __shfl_xor(sq, off);
        }
        float mean = s * 0.0078125f;
        float var  = sq * 0.0078125f - mean*mean;
        float rstd = rsqrtf(var + 1e-5f);
        hbuf[n][lane]    = __float2bfloat16((va[i]-mean)*rstd*g0 + e0);
        hbuf[n][lane+64] = __float2bfloat16((vb[i]-mean)*rstd*g1 + e1);
      }
    }
  }
  __syncthreads();   // B1

  // ---- phase 2a: K tile + V tile (one 16-feature tile each per wave) ----
  {
    f32x4 kacc[4] = {}, vacc[4] = {};
    #pragma unroll
    for (int ks = 0; ks < 4; ++ks) {
      short8 hf[4];
      #pragma unroll
      for (int mt = 0; mt < 4; ++mt)
        hf[mt] = *(const short8*)(&hbuf[mt*16 + l15][ks*32 + quad*8]);
      short8 wfk = *(const short8*)(qkvwb + (128 + wave*16 + l15)*128 + ks*32 + quad*8);
      short8 wfv = *(const short8*)(qkvwb + (256 + wave*16 + l15)*128 + ks*32 + quad*8);
      #pragma unroll
      for (int mt = 0; mt < 4; ++mt) {
        kacc[mt] = __builtin_amdgcn_mfma_f32_16x16x32_bf16(wfk, hf[mt], kacc[mt], 0, 0, 0);  // D[f][m]
        vacc[mt] = __builtin_amdgcn_mfma_f32_16x16x32_bf16(hf[mt], wfv, vacc[mt], 0, 0, 0);  // D[m][f]
      }
    }
    // K epilogue -> Kl[m][f] token-major (stride 136, m<49 guard)
    {
      const int fo = wave*16 + quad*4;   // global K feature 0..127
      float bb[4];
      #pragma unroll
      for (int r = 0; r < 4; ++r) bb[r] = qkvb[128 + fo + r];
      #pragma unroll
      for (int mt = 0; mt < 4; ++mt) {
        int m = mt*16 + l15;
        if (m < 49) {
          short4v pkv;
          #pragma unroll
          for (int r = 0; r < 4; ++r) pkv[r] = f2bs(kacc[mt][r] + bb[r]);
          *(short4v*)(Kl + m*136 + fo) = pkv;
        }
      }
    }
    // V epilogue -> vTl swizzled [hh][d][m], zero-pad m>=49
    {
      const int fv = wave*16 + l15;
      const int hh = wave >> 1, d = fv & 31;
      const float bia = qkvb[256 + fv];
      #pragma unroll
      for (int mt = 0; mt < 4; ++mt) {
        int m0 = mt*16 + quad*4;
        #pragma unroll
        for (int r = 0; r < 4; ++r) {
          int m = m0 + r;
          float v = (m < 49) ? (vacc[mt][r] + bia) : 0.f;
          vTl[(hh*32 + d)*64 + ((((m>>3) ^ (d & 7))) << 3) + (m & 7)] = __float2bfloat16(v);
        }
      }
    }
  }

  // ---- phase 2b: Q (this wave's n-half only) -> register B-fragments ----
  Frag qfr[2];
  {
    f32x4 qacc[2][2] = {};   // [tq][nt], D[f][m] with m-tiles half*2+nt
    #pragma unroll
    for (int ks = 0; ks < 4; ++ks) {
      short8 hfq[2];
      #pragma unroll
      for (int nt = 0; nt < 2; ++nt)
        hfq[nt] = *(const short8*)(&hbuf[(half*2 + nt)*16 + l15][ks*32 + quad*8]);
      #pragma unroll
      for (int tq = 0; tq < 2; ++tq) {
        short8 wf = *(const short8*)(qkvwb + ((h*2 + tq)*16 + l15)*128 + ks*32 + quad*8);
        #pragma unroll
        for (int nt = 0; nt < 2; ++nt)
          qacc[tq][nt] = __builtin_amdgcn_mfma_f32_16x16x32_bf16(wf, hfq[nt], qacc[tq][nt], 0, 0, 0);
      }
    }
    const float qs = 0.17677669529663687f;
    unsigned pkq[2][2][2];
    #pragma unroll
    for (int tq = 0; tq < 2; ++tq) {
      float bb[4];
      #pragma unroll
      for (int r = 0; r < 4; ++r) bb[r] = qkvb[h*32 + tq*16 + quad*4 + r];
      #pragma unroll
      for (int nt = 0; nt < 2; ++nt)
        #pragma unroll
        for (int i = 0; i < 2; ++i) {
          unsigned lo = (unsigned short)f2bs((qacc[tq][nt][2*i]   + bb[2*i])   * qs);
          unsigned hi = (unsigned short)f2bs((qacc[tq][nt][2*i+1] + bb[2*i+1]) * qs);
          pkq[tq][nt][i] = lo | (hi << 16);
        }
    }
    // D[f][m] -> B-frag[n][d]: quad-group exchange (same l15 = token)
    #pragma unroll
    for (int nt = 0; nt < 2; ++nt)
      #pragma unroll
      for (int p = 0; p < 4; ++p) {
        int sl = (((quad & 1)*2 + (p >> 1)) << 4) | l15;
        int a  = __shfl((int)pkq[0][nt][p & 1], sl);
        int c2 = __shfl((int)pkq[1][nt][p & 1], sl);
        qfr[nt].i[p] = (quad >= 2) ? c2 : a;
      }
  }
  __syncthreads();   // B2: K, vT ready

  // ---- phase 3: attention (no internal barrier; Q/P in registers) ----
  {
    short8 kf[4];
    #pragma unroll
    for (int mt = 0; mt < 4; ++mt)
      kf[mt] = *(const short8*)(Kl + (mt*16 + l15)*136 + h*32 + quad*8);

    f32x4 sacc[4][2] = {};   // [mt][nc]: m = mt*16+quad*4+r, n = (half*2+nc)*16+l15
    #pragma unroll
    for (int mt = 0; mt < 4; ++mt)
      #pragma unroll
      for (int nc = 0; nc < 2; ++nc)
        sacc[mt][nc] = __builtin_amdgcn_mfma_f32_16x16x32_bf16(kf[mt], qfr[nc].s, sacc[mt][nc], 0, 0, 0);

    const float* bT = biasT + h*4096;
    #pragma unroll
    for (int mt = 0; mt < 4; ++mt)
      #pragma unroll
      for (int nc = 0; nc < 2; ++nc)
        #pragma unroll
        for (int r = 0; r < 4; ++r)
          sacc[mt][nc][r] += bT[(mt*16 + quad*4 + r)*64 + (half*2 + nc)*16 + l15];

    unsigned pk[4][2][2];
    #pragma unroll
    for (int nc = 0; nc < 2; ++nc) {
      float mx = -1e30f;
      #pragma unroll
      for (int mt = 0; mt < 3; ++mt)
        #pragma unroll
        for (int r = 0; r < 4; ++r) mx = fmaxf(mx, sacc[mt][nc][r]);
      mx = fmaxf(mx, (quad == 0) ? sacc[3][nc][0] : -1e30f);   // m=48 only
      mx = fmaxf(mx, __shfl_xor(mx, 16));
      mx = fmaxf(mx, __shfl_xor(mx, 32));
      float sum = 0.f;
      #pragma unroll
      for (int mt = 0; mt < 3; ++mt)
        #pragma unroll
        for (int r = 0; r < 4; ++r) {
          float e = __expf(sacc[mt][nc][r] - mx);
          sacc[mt][nc][r] = e; sum += e;
        }
      {
        float e = (quad == 0) ? __expf(sacc[3][nc][0] - mx) : 0.f;
        sacc[3][nc][0] = e; sacc[3][nc][1] = 0.f; sacc[3][nc][2] = 0.f; sacc[3][nc][3] = 0.f;
        sum += e;
      }
      sum += __shfl_xor(sum, 16);
      sum += __shfl_xor(sum, 32);
      float inv = 1.f / sum;
      #pragma unroll
      for (int mt = 0; mt < 4; ++mt)
        #pragma unroll
        for (int i = 0; i < 2; ++i) {
          unsigned lo = (unsigned short)f2bs(sacc[mt][nc][2*i]   * inv);
          unsigned hi = (unsigned short)f2bs(sacc[mt][nc][2*i+1] * inv);
          pk[mt][nc][i] = lo | (hi << 16);
        }
    }
    // P: D[m][n] -> B-frag[n][m] in-register (quad-group exchange)
    Frag pfr[2][2];
    #pragma unroll
    for (int kt = 0; kt < 2; ++kt)
      #pragma unroll
      for (int nc = 0; nc < 2; ++nc)
        #pragma unroll
        for (int p = 0; p < 4; ++p) {
          int sl = (((quad & 1)*2 + (p >> 1)) << 4) | l15;
          int a  = __shfl((int)pk[kt*2    ][nc][p & 1], sl);
          int c2 = __shfl((int)pk[kt*2 + 1][nc][p & 1], sl);
          pfr[kt][nc].i[p] = (quad >= 2) ? c2 : a;
        }

    // AV: A=V^T rows d (swizzled vT), B=P rows n -> D[d][n]
    f32x4 oacc[2][2] = {};
    #pragma unroll
    for (int kt = 0; kt < 2; ++kt) {
      short8 vf[2];
      #pragma unroll
      for (int dt = 0; dt < 2; ++dt)
        vf[dt] = *(const short8*)(vTl + (h*32 + dt*16 + l15)*64 + (((kt*4 + quad) ^ (l15 & 7)) << 3));
      #pragma unroll
      for (int dt = 0; dt < 2; ++dt)
        #pragma unroll
        for (int nc = 0; nc < 2; ++nc)
          oacc[dt][nc] = __builtin_amdgcn_mfma_f32_16x16x32_bf16(vf[dt], pfr[kt][nc].s, oacc[dt][nc], 0, 0, 0);
    }
    #pragma unroll
    for (int dt = 0; dt < 2; ++dt)
      #pragma unroll
      for (int nc = 0; nc < 2; ++nc) {
        int n = (half*2 + nc)*16 + l15;
        if (n < 49) {
          short4v pkv;
          #pragma unroll
          for (int r = 0; r < 4; ++r) pkv[r] = f2bs(oacc[dt][nc][r]);
          *(short4v*)(&hbuf[n][h*32 + dt*16 + quad*4]) = pkv;
        }
      }
  }
  __syncthreads();   // B3: hbuf-o ready; K/vT dead -> x2s region free

  // ---- phase 4: proj + shortcut -> x2 in REGISTERS + fp32 x2s (overlay) ----
  f32x4 x2v[4];   // [mt]: m = mt*16+quad*4+r, f = wave*16+l15
  {
    const int n = wave * 16 + l15;
    float xres[4][4];
    #pragma unroll
    for (int mt = 0; mt < 4; ++mt) {
      #pragma unroll
      for (int r = 0; r < 4; ++r) {
        int m = mt*16 + quad*4 + r;
        float v = 0.f;
        if (m < 49) {
          int rr = m / 7, cc = m - rr * 7;
          int si = wi*7 + rr + 3; if (si >= 56) si -= 56;
          int sj = wj*7 + cc + 3; if (sj >= 56) sj -= 56;
          v = x[(b*3136 + si*56 + sj) * 128 + n];
        }
        xres[mt][r] = v;
      }
    }
    f32x4 acc[4] = {};
    #pragma unroll
    for (int ks = 0; ks < 4; ++ks) {
      short8 af[4];
      #pragma unroll
      for (int mt = 0; mt < 4; ++mt)
        af[mt] = *(const short8*)(&hbuf[mt*16 + l15][ks*32 + quad*8]);
      short8 bfr = *(const short8*)(projwb + n*128 + ks*32 + quad*8);
      #pragma unroll
      for (int mt = 0; mt < 4; ++mt)
        acc[mt] = __builtin_amdgcn_mfma_f32_16x16x32_bf16(af[mt], bfr, acc[mt], 0, 0, 0);
    }
    float pbv = projb[n];
    #pragma unroll
    for (int mt = 0; mt < 4; ++mt) {
      #pragma unroll
      for (int r = 0; r < 4; ++r) {
        int m = mt*16 + quad*4 + r;
        float v = 0.f;
        if (m < 49) v = acc[mt][r] + pbv + xres[mt][r];
        x2v[mt][r] = v;
        x2s[m*132 + n] = v;
      }
    }
  }
  __syncthreads();   // B4: x2s ready

  // ---- phase 5: LN2 from x2s -> hbuf bf16 ----
  {
    float g0 = n2g[lane], g1 = n2g[lane+64], e0 = n2b[lane], e1 = n2b[lane+64];
    for (int n = wave; n < 49; n += 8) {
      float v0 = x2s[n*132 + lane], v1 = x2s[n*132 + lane + 64];
      float s = v0 + v1, sq = v0*v0 + v1*v1;
      #pragma unroll
      for (int off = 32; off > 0; off >>= 1) {
        s  += __shfl_xor(s,  off);
        sq += __shfl_xor(sq, off);
      }
      float mean = s * 0.0078125f;
      float var  = sq * 0.0078125f - mean*mean;
      float rstd = rsqrtf(var + 1e-5f);
      hbuf[n][lane]    = __float2bfloat16((v0-mean)*rstd*g0 + e0);
      hbuf[n][lane+64] = __float2bfloat16((v1-mean)*rstd*g1 + e1);
    }
    __hip_bfloat16 z = __float2bfloat16(0.f);
    for (int n = 49 + wave; n < 64; n += 8) {   // zero pad rows for GEMM1
      hbuf[n][lane] = z; hbuf[n][lane+64] = z;
    }
  }
  __syncthreads();   // B5: ln ready; x2s dead -> hb dbuf region free

  // ---- phase 6: MLP, hidden in 4 chunks of 128, double-buffered ----
  f32x4 acc2[4] = {};   // [mt]: m = mt*16+quad*4+r, f = wave*16+l15
  const int fb2 = wave * 16;

  auto G1 = [&](int c, __hip_bfloat16* dst) {
    const int jg = c*128 + wave*16;
    f32x4 a1[4] = {};
    #pragma unroll
    for (int ks = 0; ks < 4; ++ks) {
      short8 lf[4];
      #pragma unroll
      for (int mt = 0; mt < 4; ++mt)
        lf[mt] = *(const short8*)(&hbuf[mt*16 + l15][ks*32 + quad*8]);
      short8 wf = *(const short8*)(w1b + (jg + l15)*128 + ks*32 + quad*8);
      #pragma unroll
      for (int mt = 0; mt < 4; ++mt)
        a1[mt] = __builtin_amdgcn_mfma_f32_16x16x32_bf16(wf, lf[mt], a1[mt], 0, 0, 0);  // D[j][m]
    }
    float bb[4];
    #pragma unroll
    for (int r = 0; r < 4; ++r) bb[r] = b1[jg + quad*4 + r];
    #pragma unroll
    for (int mt = 0; mt < 4; ++mt) {
      int m = mt*16 + l15;
      short4v pkv;
      #pragma unroll
      for (int r = 0; r < 4; ++r) pkv[r] = f2bs(gelu_f(a1[mt][r] + bb[r]));
      *(short4v*)(dst + m*136 + wave*16 + quad*4) = pkv;
    }
  };
  auto G2 = [&](int c, const __hip_bfloat16* src) {
    #pragma unroll
    for (int ks = 0; ks < 4; ++ks) {
      short8 af[4];
      #pragma unroll
      for (int mt = 0; mt < 4; ++mt)
        af[mt] = *(const short8*)(src + (mt*16 + l15)*136 + ks*32 + quad*8);
      short8 wf = *(const short8*)(w2b + (fb2 + l15)*512 + c*128 + ks*32 + quad*8);
      #pragma unroll
      for (int mt = 0; mt < 4; ++mt)
        acc2[mt] = __builtin_amdgcn_mfma_f32_16x16x32_bf16(af[mt], wf, acc2[mt], 0, 0, 0);
    }
  };

  G1(0, hbA);
  __syncthreads();            // B6
  G1(1, hbB); G2(0, hbA);
  __syncthreads();            // B7
  G1(2, hbA); G2(1, hbB);
  __syncthreads();            // B8
  G1(3, hbB); G2(2, hbA);
  __syncthreads();            // B9
  G2(3, hbB);

  // ---- epilogue: bias + register residual, scatter (roll +3) ----
  {
    const int f = fb2 + l15;
    const float bb = b2[f];
    #pragma unroll
    for (int mt = 0; mt < 4; ++mt) {
      #pragma unroll
      for (int r = 0; r < 4; ++r) {
        int m = mt*16 + quad*4 + r;
        if (m < 49) {
          int rr = m / 7, cc = m - rr * 7;
          int si = wi*7 + rr + 3; if (si >= 56) si -= 56;
          int sj = wj*7 + cc + 3; if (sj >= 56) sj -= 56;
          int o = (b*3136 + si*56 + sj) * 128 + f;
          out[o] = acc2[mt][r] + bb + x2v[mt][r];
        }
      }
    }
  }
}

extern "C" void kernel_launch(void* const* d_in, const int* in_sizes, int n_in,
                              void* d_out, int out_size, void* d_ws, size_t ws_size,
                              hipStream_t stream) {
  const float* x     = (const float*)d_in[0];
  const float* n1g   = (const float*)d_in[3];
  const float* n1b   = (const float*)d_in[4];
  const float* qkvw  = (const float*)d_in[5];
  const float* qkvb  = (const float*)d_in[6];
  const float* tab   = (const float*)d_in[7];
  const int*   ridx  = (const int*)d_in[8];
  const float* projw = (const float*)d_in[9];
  const float* projb = (const float*)d_in[10];
  const float* n2g   = (const float*)d_in[11];
  const float* n2b   = (const float*)d_in[12];
  const float* w1    = (const float*)d_in[13];
  const float* b1    = (const float*)d_in[14];
  const float* w2    = (const float*)d_in[15];
  const float* b2    = (const float*)d_in[16];
  float* outp = (float*)d_out;

  __hip_bfloat16* wsb = (__hip_bfloat16*)d_ws;
  float* biasT = (float*)((char*)d_ws + BIAS_BYTE_OFF);

  hipLaunchKernelGGL(conv_kernel, dim3(832), dim3(256), 0, stream,
                     qkvw, projw, w1, w2, tab, ridx, wsb, biasT);
  hipLaunchKernelGGL(fused_kernel, dim3(NWIN), dim3(512), 0, stream,
                     x, n1g, n1b, wsb + QKVW_OFF, qkvb, biasT, wsb + PROJW_OFF, projb,
                     n2g, n2b, wsb + W1_OFF, b1, wsb + W2_OFF, b2, outp);
}